// Round 11
// baseline (66.741 us; speedup 1.0000x reference)
//
#include <hip/hip_runtime.h>

namespace {
constexpr int Bv = 8;
constexpr int Nv = 2048;
constexpr int Dv = 256;
constexpr float SCALE = 0.1f;
constexpr float PSCALE = 256.0f;          // P quant scale (fp8 normal range)
constexpr float OSC = SCALE / PSCALE;     // epilogue un-scale
constexpr float LN_EPS = 1e-6f;
constexpr float NORM_EPS = 1e-12f;
}

typedef unsigned char u8;
typedef unsigned int u32;
typedef __attribute__((ext_vector_type(4))) float f32x4;

#define SBAR()   asm volatile("s_barrier" ::: "memory")
#define WAITV(N) asm volatile("s_waitcnt vmcnt(" #N ")" ::: "memory")
#define WAITL()  asm volatile("s_waitcnt lgkmcnt(0)" ::: "memory")
#define CFENCE() asm volatile("" ::: "memory")

// global -> LDS direct DMA, 16B/lane. lds base wave-uniform; HW adds lane*16.
__device__ __forceinline__ void gll16(const void* g, void* l) {
    __builtin_amdgcn_global_load_lds(
        (__attribute__((address_space(1))) void*)(uintptr_t)g,
        (__attribute__((address_space(3))) void*)(uintptr_t)l, 16, 0, 0);
}
// pack 4 f32 -> 4 fp8 e4m3 bytes
__device__ __forceinline__ u32 pk4(float a, float b, float c, float d) {
    u32 w = __builtin_amdgcn_cvt_pk_fp8_f32(a, b, 0, false);
    return __builtin_amdgcn_cvt_pk_fp8_f32(c, d, w, true);
}

// ---------------------------------------------------------------------------
// 1) Fused prep. Outputs: xn8 row-major fp8 (L2-normalized rows) and
//    xT8 row-major fp8 (raw x transposed, [b][d][n]). Block = 64 rows x 256 d.
__global__ __launch_bounds__(512) void k_prepT(const float* __restrict__ x,
                                               u8* __restrict__ xn8,
                                               u8* __restrict__ xT8) {
    __shared__ u8 lt[64][272];   // raw-x fp8 [n_local][d]
    const int b = blockIdx.x >> 5;
    const int n0 = (blockIdx.x & 31) * 64;
    const int t = threadIdx.x;
    const int r = t >> 3, c0 = (t & 7) * 32;
    const float* xr = x + ((size_t)b * Nv + n0 + r) * Dv + c0;
    float4 v[8];
    float ss = 0.f;
#pragma unroll
    for (int i = 0; i < 8; ++i) {
        v[i] = ((const float4*)xr)[i];
        ss += v[i].x * v[i].x + v[i].y * v[i].y + v[i].z * v[i].z + v[i].w * v[i].w;
    }
#pragma unroll
    for (int m = 1; m < 8; m <<= 1) ss += __shfl_xor(ss, m, 64);
    const float inv = 1.0f / fmaxf(sqrtf(ss), NORM_EPS);
    u32 wn[8];
#pragma unroll
    for (int i = 0; i < 8; ++i) {
        wn[i] = pk4(v[i].x * inv, v[i].y * inv, v[i].z * inv, v[i].w * inv);
        *(u32*)&lt[r][c0 + i * 4] = pk4(v[i].x, v[i].y, v[i].z, v[i].w);
    }
    {   // xn8 row-major
        uint4 o0 = {wn[0], wn[1], wn[2], wn[3]};
        uint4 o1 = {wn[4], wn[5], wn[6], wn[7]};
        u8* xnr = xn8 + ((size_t)b * Nv + n0 + r) * Dv + c0;
        *(uint4*)xnr = o0;
        *(uint4*)(xnr + 16) = o1;
    }
    __syncthreads();
    {   // xT8 row-major [d][n]: thread handles d = t>>1, n-half h = t&1
        const int d = t >> 1, h = t & 1;
        u32 w2[8];
#pragma unroll
        for (int q = 0; q < 8; ++q) {
            const int nb = h * 32 + q * 4;
            w2[q] = (u32)lt[nb][d] | ((u32)lt[nb + 1][d] << 8) |
                    ((u32)lt[nb + 2][d] << 16) | ((u32)lt[nb + 3][d] << 24);
        }
        uint4 p0 = {w2[0], w2[1], w2[2], w2[3]};
        uint4 p1 = {w2[4], w2[5], w2[6], w2[7]};
        u8* xtr = xT8 + ((size_t)b * Dv + d) * Nv + n0 + h * 32;
        *(uint4*)xtr = p0;
        *(uint4*)(xtr + 16) = p1;
    }
}

// ---------------------------------------------------------------------------
// 2) E = exp(xn@xn^T - 1) fp8, row-panel blocks (32 rows x all 2048 cols).
//    T4 pipeline: counted vmcnt(5), raw barriers, loads span phases.
//    Per chunk: {MFMA + exp->eS | E-store + stage chunk+2}.
__global__ __launch_bounds__(512, 4) void k_gemm1(const u8* __restrict__ xn8,
                                                  u8* __restrict__ E,
                                                  float* __restrict__ rl) {
    __shared__ u8 Bs[2][128 * 256];   // 2 x 32 KB
    __shared__ u8 eS[2][128 * 40];    // [m-col][32 n + pad8], 2 x 5 KB
    __shared__ float red[32][4];
    const int wg = blockIdx.x;        // 512: XCD owns one batch
    const int b = wg & 7, bi = wg >> 3;            // bi 0..63 (32-row panel)
    const int t = threadIdx.x;
    const int wave = t >> 6, lane = t & 63;
    const int wr = wave >> 2, wc = wave & 3;       // wave tile 16r x 32c
    const int l15 = lane & 15, kl = lane >> 4;
    const u8* xb = xn8 + (size_t)b * (Nv * Dv);
    u8* Eb = E + (size_t)b * Nv * Nv;
    const int sc = t >> 2, sg = t & 3;

    auto stageB = [&](int buf, int ch) {   // 128 rows x 256B, swizzled source
#pragma unroll
        for (int c = 0; c < 4; ++c) {
            const int row = wave * 16 + c * 4 + (lane >> 4);
            const int slot = (lane & 15) ^ (row & 15);
            gll16(xb + (size_t)(ch * 128 + row) * Dv + slot * 16,
                  Bs[buf] + wave * 4096 + c * 1024);
        }
    };
    auto bfrag = [&](const u8* base, int row, int kk) -> long {
        const int slot = kk * 2 + (kl >> 1);
        return *(const long*)(base + row * 256 +
                              ((slot ^ (row & 15)) << 4) + ((kl & 1) << 3));
    };

    const int ch0 = bi >> 2;
    stageB(0, ch0);
    CFENCE();
    stageB(1, (ch0 + 1) & 15);
    WAITV(4); SBAR();
    long af[8];
    {
        const int arow = (bi & 3) * 32 + wr * 16 + l15;
#pragma unroll
        for (int kk = 0; kk < 8; ++kk) af[kk] = bfrag(Bs[0], arow, kk);
    }
    float rs[4] = {0.f, 0.f, 0.f, 0.f};

    auto phaseA = [&](int cur) {           // MFMA chunk + exp -> eS[cur]
        f32x4 acc[2] = {};
        __builtin_amdgcn_s_setprio(1);
#pragma unroll
        for (int kk = 0; kk < 8; ++kk) {
            const long b0 = bfrag(Bs[cur], wc * 32 + l15, kk);
            const long b1 = bfrag(Bs[cur], wc * 32 + 16 + l15, kk);
            acc[0] = __builtin_amdgcn_mfma_f32_16x16x32_fp8_fp8(af[kk], b0, acc[0], 0, 0, 0);
            acc[1] = __builtin_amdgcn_mfma_f32_16x16x32_fp8_fp8(af[kk], b1, acc[1], 0, 0, 0);
        }
        __builtin_amdgcn_s_setprio(0);
#pragma unroll
        for (int j = 0; j < 2; ++j) {
            const int col = wc * 32 + j * 16 + l15;
            const float e0 = __expf(acc[j][0] - 1.0f);
            const float e1 = __expf(acc[j][1] - 1.0f);
            const float e2 = __expf(acc[j][2] - 1.0f);
            const float e3 = __expf(acc[j][3] - 1.0f);
            rs[0] += e0; rs[1] += e1; rs[2] += e2; rs[3] += e3;
            *(u32*)&eS[cur][col * 40 + wr * 16 + kl * 4] = pk4(e0, e1, e2, e3);
        }
    };
    auto estore = [&](int cur, int ch) {
        *(uint2*)&Eb[(size_t)(ch * 128 + sc) * Nv + bi * 32 + sg * 8] =
            *(const uint2*)&eS[cur][sc * 40 + sg * 8];
    };

    for (int cc = 0; cc < 14; ++cc) {
        const int cur = cc & 1;
        phaseA(cur);
        WAITL(); SBAR();
        estore(cur, (ch0 + cc) & 15);          // 1 vmem store
        stageB(cur, (ch0 + cc + 2) & 15);      // 4 vmem loads
        WAITV(5); SBAR();                      // chunk cc+1's group retired
    }
    // cc = 14
    phaseA(0);
    WAITL(); SBAR();
    estore(0, (ch0 + 14) & 15);
    WAITV(1); SBAR();                          // chunk 15's stage retired
    // cc = 15
    phaseA(1);
    WAITL(); SBAR();
    estore(1, (ch0 + 15) & 15);
    // rl reduction: plain write, no atomics.
#pragma unroll
    for (int r = 0; r < 4; ++r) {
        float v = rs[r];
#pragma unroll
        for (int m = 1; m < 16; m <<= 1) v += __shfl_xor(v, m, 64);
        if (l15 == 0) red[wr * 16 + kl * 4 + r][wc] = v;
    }
    __syncthreads();
    if (t < 32)
        rl[b * Nv + bi * 32 + t] =
            PSCALE * __builtin_amdgcn_rcpf(red[t][0] + red[t][1] + red[t][2] + red[t][3]);
}

// ---------------------------------------------------------------------------
// 3) x_neg = P @ x, P[n,m] = E[n,m]*(rl_n + rl_m), fused LN epilogue.
//    T4 pipeline: per kt {MFMA + wstore(P) | load E/rl + stage B}, counted
//    vmcnt(7) (1 E + 2 rl + 4 gll16 per phase-group), raw barriers.
__global__ __launch_bounds__(512) void k_gemm2ln(const u8* __restrict__ E,
                                                 const float* __restrict__ rl,
                                                 const u8* __restrict__ xT8,
                                                 const float* __restrict__ x,
                                                 const float* __restrict__ gamma,
                                                 const float* __restrict__ beta,
                                                 float* __restrict__ out) {
    __shared__ u8 Bs[2][256 * 128];   // 64 KB
    __shared__ u8 Ps[2][32 * 136];    // 8.5 KB
    __shared__ float red[32][8][2];   // 2 KB
    const int wg = blockIdx.x;        // 512: XCD owns one batch
    const int swz = (wg & 7) * 64 + (wg >> 3);
    const int b = swz >> 6, bi = swz & 63;         // 32-row panel
    const int t = threadIdx.x;
    const int wave = t >> 6, lane = t & 63;
    const int l15 = lane & 15, kl = lane >> 4;
    const int srow = t >> 4, s16 = t & 15;         // P staging: 16 thr/row
    const float* rlb = rl + (size_t)b * Nv;
    const u8* Erow = E + ((size_t)b * Nv + bi * 32 + srow) * Nv + s16 * 8;
    const u8* xtb = xT8 + (size_t)b * 524288;

    auto issueB = [&](int buf, int kt) {   // stage 256 d-rows x 128B (4 gll16)
#pragma unroll
        for (int c = 0; c < 4; ++c) {
            const int row = c * 64 + wave * 8 + (lane >> 3);
            const int slot = (lane & 7) ^ (row & 7);
            gll16(xtb + (size_t)row * Nv + kt * 128 + slot * 16,
                  (char*)Bs[buf] + c * 8192 + wave * 1024);
        }
    };
    auto bfragB = [&](const u8* base, int d, int kk) -> long {
        const int s = kk * 2 + (kl >> 1);
        return *(const long*)(base + d * 128 + ((s ^ (d & 7)) << 4) + ((kl & 1) << 3));
    };
    auto afrag = [&](const u8* base, int row, int kk) -> long {
        return *(const long*)(base + row * 136 + kk * 32 + kl * 8);
    };

    const float linv_n = rlb[bi * 32 + srow];
    auto wstore = [&](u8* pbuf, uint2 ev, float4 ra, float4 rb) {
        const u32 o0 = pk4(__builtin_amdgcn_cvt_f32_fp8(ev.x, 0) * (linv_n + ra.x),
                           __builtin_amdgcn_cvt_f32_fp8(ev.x, 1) * (linv_n + ra.y),
                           __builtin_amdgcn_cvt_f32_fp8(ev.x, 2) * (linv_n + ra.z),
                           __builtin_amdgcn_cvt_f32_fp8(ev.x, 3) * (linv_n + ra.w));
        const u32 o1 = pk4(__builtin_amdgcn_cvt_f32_fp8(ev.y, 0) * (linv_n + rb.x),
                           __builtin_amdgcn_cvt_f32_fp8(ev.y, 1) * (linv_n + rb.y),
                           __builtin_amdgcn_cvt_f32_fp8(ev.y, 2) * (linv_n + rb.z),
                           __builtin_amdgcn_cvt_f32_fp8(ev.y, 3) * (linv_n + rb.w));
        uint2 o = {o0, o1};
        *(uint2*)(pbuf + srow * 136 + s16 * 8) = o;
    };
    auto loadgrp = [&](int nk, uint2& ev, float4& ra, float4& rb) {  // 3 vmem
        ev = *(const uint2*)(Erow + nk * 128);
        ra = *(const float4*)&rlb[nk * 128 + s16 * 8];
        rb = *(const float4*)&rlb[nk * 128 + s16 * 8 + 4];
    };

    f32x4 acc[2][2] = {};
    auto phaseA = [&](int cur) {
        __builtin_amdgcn_s_setprio(1);
#pragma unroll
        for (int kk = 0; kk < 4; ++kk) {
            const long a0 = afrag(Ps[cur], l15, kk);
            const long a1 = afrag(Ps[cur], 16 + l15, kk);
            const long b0 = bfragB(Bs[cur], wave * 32 + l15, kk);
            const long b1 = bfragB(Bs[cur], wave * 32 + 16 + l15, kk);
            acc[0][0] = __builtin_amdgcn_mfma_f32_16x16x32_fp8_fp8(a0, b0, acc[0][0], 0, 0, 0);
            acc[0][1] = __builtin_amdgcn_mfma_f32_16x16x32_fp8_fp8(a0, b1, acc[0][1], 0, 0, 0);
            acc[1][0] = __builtin_amdgcn_mfma_f32_16x16x32_fp8_fp8(a1, b0, acc[1][0], 0, 0, 0);
            acc[1][1] = __builtin_amdgcn_mfma_f32_16x16x32_fp8_fp8(a1, b1, acc[1][1], 0, 0, 0);
        }
        __builtin_amdgcn_s_setprio(0);
    };

    // prologue: 2 groups in flight
    uint2 evA, evB2;
    float4 raA, rbA, raB2, rbB2;
    loadgrp(0, evA, raA, rbA);
    issueB(0, 0);
    CFENCE();
    loadgrp(1, evB2, raB2, rbB2);
    issueB(1, 1);
    CFENCE();
    wstore(Ps[0], evA, raA, rbA);
    WAITL(); WAITV(7); SBAR();     // group0 (incl. linv) retired; Ps[0] published

    for (int kt2 = 0; kt2 < 7; ++kt2) {
        // kt = 2*kt2 (cur = 0)
        phaseA(0);
        wstore(Ps[1], evB2, raB2, rbB2);
        WAITL(); SBAR();
        loadgrp(2 * kt2 + 2, evA, raA, rbA);
        issueB(0, 2 * kt2 + 2);
        WAITV(7); SBAR();
        // kt = 2*kt2+1 (cur = 1)
        phaseA(1);
        wstore(Ps[0], evA, raA, rbA);
        WAITL(); SBAR();
        loadgrp(2 * kt2 + 3, evB2, raB2, rbB2);
        issueB(1, 2 * kt2 + 3);
        WAITV(7); SBAR();
    }
    // kt = 14
    phaseA(0);
    wstore(Ps[1], evB2, raB2, rbB2);
    WAITL(); SBAR();
    WAITV(0); SBAR();              // chunk 15's stage fully retired
    // kt = 15
    phaseA(1);

    // epilogue: v = x - OSC*acc, LN across the 8 waves (32 cols each).
    const float* xb = x + ((size_t)b * Nv + bi * 32) * Dv;
    float tv[2][2][4];
#pragma unroll
    for (int i = 0; i < 2; ++i) {
#pragma unroll
        for (int r = 0; r < 4; ++r) {
            const int rr = i * 16 + kl * 4 + r;
            float s1 = 0.f, s2 = 0.f;
#pragma unroll
            for (int j = 0; j < 2; ++j) {
                const int cc = wave * 32 + j * 16 + l15;
                const float v = xb[(size_t)rr * Dv + cc] - OSC * acc[i][j][r];
                tv[i][j][r] = v;
                s1 += v; s2 += v * v;
            }
#pragma unroll
            for (int m = 1; m < 16; m <<= 1) {
                s1 += __shfl_xor(s1, m, 64);
                s2 += __shfl_xor(s2, m, 64);
            }
            if (l15 == 0) { red[rr][wave][0] = s1; red[rr][wave][1] = s2; }
        }
    }
    __syncthreads();
#pragma unroll
    for (int i = 0; i < 2; ++i) {
#pragma unroll
        for (int r = 0; r < 4; ++r) {
            const int rr = i * 16 + kl * 4 + r;
            float s1 = 0.f, s2 = 0.f;
#pragma unroll
            for (int w = 0; w < 8; ++w) { s1 += red[rr][w][0]; s2 += red[rr][w][1]; }
            const float mu = s1 * (1.0f / Dv);
            const float var = s2 * (1.0f / Dv) - mu * mu;
            const float rstd = rsqrtf(var + LN_EPS);
#pragma unroll
            for (int j = 0; j < 2; ++j) {
                const int cc = wave * 32 + j * 16 + l15;
                out[((size_t)b * Nv + bi * 32 + rr) * Dv + cc] =
                    (tv[i][j][r] - mu) * rstd * gamma[cc] + beta[cc];
            }
        }
    }
}

// ---------------------------------------------------------------------------
extern "C" void kernel_launch(void* const* d_in, const int* in_sizes, int n_in,
                              void* d_out, int out_size, void* d_ws, size_t ws_size,
                              hipStream_t stream) {
    const float* x = (const float*)d_in[0];
    const float* gamma = (const float*)d_in[1];
    const float* beta = (const float*)d_in[2];
    float* out = (float*)d_out;
    char* ws = (char*)d_ws;
    u8* xn8 = (u8*)ws;                        // 4.2 MB row-major fp8
    u8* xT8 = (u8*)(ws + 4194304);            // 4.2 MB row-major fp8 [d][n]
    float* rl = (float*)(ws + 8388608);       // 64 KB: PSCALE / l_n
    u8* E = (u8*)(ws + 8454144);              // 33.5 MB fp8, row-major

    k_prepT<<<Bv * (Nv / 64), 512, 0, stream>>>(x, xn8, xT8);
    k_gemm1<<<Bv * (Nv / 32), 512, 0, stream>>>(xn8, E, rl);
    k_gemm2ln<<<Bv * (Nv / 32), 512, 0, stream>>>(E, rl, xT8, x, gamma, beta, out);
}